// Round 6
// baseline (350.561 us; speedup 1.0000x reference)
//
#include <hip/hip_runtime.h>
#include <float.h>
#include <math.h>

// KNNAttention: b=4, l=2048, d=1024, h=16, dh=64, n_mem=1000
#define BATCH 4
#define SEQ   2048
#define DIM   1024
#define NHEAD 16
#define DHEAD 64
#define NMEM  1000
#define NPAD  1024          // padded memory slots
#define ROWS  (BATCH*SEQ)   // 8192
// qp pre-scale: 0.125 * log2(e); softmax becomes exp2(S + log2(count))
#define QSCALE 0.18033688011112042f

typedef __attribute__((ext_vector_type(8))) __bf16 bf16x8;
typedef __attribute__((ext_vector_type(4))) __bf16 bf16x4;
typedef __attribute__((ext_vector_type(4))) float  f32x4;

static __device__ inline f32x4 mfma16(bf16x8 a, bf16x8 b, f32x4 c) {
  return __builtin_amdgcn_mfma_f32_16x16x32_bf16(a, b, c, 0, 0, 0);
}

// async global->LDS, 16B per lane. LDS dest must be wave-uniform base (+lane*16).
#define GLOAD16(g, l) __builtin_amdgcn_global_load_lds( \
    (const __attribute__((address_space(1))) unsigned int*)(g), \
    (__attribute__((address_space(3))) unsigned int*)(l), 16, 0, 0)

enum { MODE_C = 0, MODE_HILO = 1, MODE_ARGMAX = 2, MODE_KV = 3 };

// ---------------------------------------------------------------------------
// Fused split-bf16 GEMM (verified rounds 2-5): C = A * B^T, up to 3 products.
// MODE_HILO additionally scales by QSCALE (argmax is scale-invariant; the
// attention consumes exp2-domain logits).
// MODE_KV: cols 0-63 -> Ktab row-major; cols 64-127 -> VtT [b][d][n'] with n'
// the within-64 permutation n' = (n&15)*4 + (n>>4)&3 (matches attn's P store).
// ---------------------------------------------------------------------------
template<int AF32, int NPROD, int MODE>
__global__ __launch_bounds__(256) void gemm3(
    const void* __restrict__ Ah_, const __bf16* __restrict__ Al,
    const __bf16* __restrict__ Bh, const __bf16* __restrict__ Bl,
    int rowsPerZ, long bStrideZ,
    float* __restrict__ C, __bf16* __restrict__ Oh, __bf16* __restrict__ Ol,
    float* __restrict__ pv, int* __restrict__ pi)
{
  extern __shared__ char smem[];
  __shared__ float s_pv[128];
  __shared__ int   s_pi[128];
  const int t = threadIdx.x;
  const int w = t >> 6, lane = t & 63, l15 = lane & 15, g = lane >> 4;
  const int wr = w >> 1, wc = w & 1;
  const int m0 = blockIdx.z * rowsPerZ + blockIdx.x * 128;
  const int n0 = blockIdx.y * 128;
  const __bf16* Bh_b = Bh + (size_t)blockIdx.z * bStrideZ;
  const __bf16* Bl_b = (NPROD == 3) ? (Bl + (size_t)blockIdx.z * bStrideZ) : (const __bf16*)0;

  char* sA  = smem;
  char* sAl = smem + 8192;
  char* sBh = smem + (AF32 ? 16384 : (NPROD == 3 ? 16384 : 8192));
  char* sBl = sBh + 8192;

  f32x4 acc[4][4];
  #pragma unroll
  for (int i = 0; i < 4; ++i)
    #pragma unroll
    for (int j = 0; j < 4; ++j) acc[i][j] = (f32x4){0.f, 0.f, 0.f, 0.f};

  for (int k0 = 0; k0 < DIM; k0 += 32) {
    if (AF32) {
      const float* Af = (const float*)Ah_;
      #pragma unroll
      for (int i = 0; i < 4; ++i) {
        int c = i * 256 + t;
        int r = c >> 3, s = c & 7;
        int sl = s ^ (r & 7);
        GLOAD16(&Af[(size_t)(m0 + r) * DIM + k0 + sl * 4], sA + i * 4096 + w * 1024);
      }
    } else {
      const __bf16* Ab = (const __bf16*)Ah_;
      #pragma unroll
      for (int i = 0; i < 2; ++i) {
        int c = i * 256 + t;
        int r = c >> 2, s = c & 3;
        int sl = s ^ (r & 3);
        GLOAD16(&Ab[(size_t)(m0 + r) * DIM + k0 + sl * 8], sA + i * 4096 + w * 1024);
        if (NPROD == 3)
          GLOAD16(&Al[(size_t)(m0 + r) * DIM + k0 + sl * 8], sAl + i * 4096 + w * 1024);
      }
    }
    #pragma unroll
    for (int i = 0; i < 2; ++i) {
      int c = i * 256 + t;
      int r = c >> 2, s = c & 3;
      int sl = s ^ (r & 3);
      GLOAD16(&Bh_b[(size_t)(n0 + r) * DIM + k0 + sl * 8], sBh + i * 4096 + w * 1024);
      if (NPROD == 3)
        GLOAD16(&Bl_b[(size_t)(n0 + r) * DIM + k0 + sl * 8], sBl + i * 4096 + w * 1024);
    }
    __syncthreads();

    bf16x8 ah[4], al[4], bh[4], bl[4];
    #pragma unroll
    for (int mi = 0; mi < 4; ++mi) {
      int r = wr * 64 + mi * 16 + l15;
      if (AF32) {
        int p0 = (2 * g) ^ (r & 7), p1 = (2 * g + 1) ^ (r & 7);
        float4 q0 = *(const float4*)(sA + r * 128 + p0 * 16);
        float4 q1 = *(const float4*)(sA + r * 128 + p1 * 16);
        float qq[8] = {q0.x, q0.y, q0.z, q0.w, q1.x, q1.y, q1.z, q1.w};
        #pragma unroll
        for (int j = 0; j < 8; ++j) {
          __bf16 h = (__bf16)qq[j];
          ah[mi][j] = h;
          al[mi][j] = (__bf16)(qq[j] - (float)h);
        }
      } else {
        int p = (g ^ (r & 3)) * 16;
        ah[mi] = *(const bf16x8*)(sA + r * 64 + p);
        if (NPROD == 3) al[mi] = *(const bf16x8*)(sAl + r * 64 + p);
      }
    }
    #pragma unroll
    for (int ni = 0; ni < 4; ++ni) {
      int r = wc * 64 + ni * 16 + l15;
      int p = (g ^ (r & 3)) * 16;
      bh[ni] = *(const bf16x8*)(sBh + r * 64 + p);
      if (NPROD == 3) bl[ni] = *(const bf16x8*)(sBl + r * 64 + p);
    }
    #pragma unroll
    for (int mi = 0; mi < 4; ++mi)
      #pragma unroll
      for (int ni = 0; ni < 4; ++ni) {
        acc[mi][ni] = mfma16(ah[mi], bh[ni], acc[mi][ni]);
        if (NPROD == 3) {
          acc[mi][ni] = mfma16(ah[mi], bl[ni], acc[mi][ni]);
          acc[mi][ni] = mfma16(al[mi], bh[ni], acc[mi][ni]);
        }
      }
    __syncthreads();
  }

  if (MODE == MODE_C) {
    #pragma unroll
    for (int mi = 0; mi < 4; ++mi)
      #pragma unroll
      for (int ni = 0; ni < 4; ++ni) {
        int col = n0 + wc * 64 + ni * 16 + l15;
        #pragma unroll
        for (int r = 0; r < 4; ++r) {
          int row = m0 + wr * 64 + mi * 16 + g * 4 + r;
          C[(size_t)row * DIM + col] = acc[mi][ni][r];
        }
      }
  } else if (MODE == MODE_HILO) {
    #pragma unroll
    for (int mi = 0; mi < 4; ++mi)
      #pragma unroll
      for (int ni = 0; ni < 4; ++ni) {
        int col = n0 + wc * 64 + ni * 16 + l15;
        #pragma unroll
        for (int r = 0; r < 4; ++r) {
          int row = m0 + wr * 64 + mi * 16 + g * 4 + r;
          float v = acc[mi][ni][r] * QSCALE;
          __bf16 h = (__bf16)v;
          Oh[(size_t)row * DIM + col] = h;
          Ol[(size_t)row * DIM + col] = (__bf16)(v - (float)h);
        }
      }
  } else if (MODE == MODE_KV) {
    // Oh = Ktab [b*NPAD+n][64], Ol = VtT [b][64][NPAD] at permuted n'
    #pragma unroll
    for (int mi = 0; mi < 4; ++mi)
      #pragma unroll
      for (int ni = 0; ni < 4; ++ni) {
        int col = wc * 64 + ni * 16 + l15;
        #pragma unroll
        for (int r = 0; r < 4; ++r) {
          int gr = m0 + wr * 64 + mi * 16 + g * 4 + r;
          int bb = gr >> 10, n = gr & (NPAD - 1);
          __bf16 h = (__bf16)acc[mi][ni][r];
          if (col < DHEAD) {
            Oh[(size_t)gr * DHEAD + col] = h;
          } else {
            int np = (n & ~63) | ((n & 15) << 2) | ((n >> 4) & 3);
            Ol[((size_t)bb * DHEAD + (col - DHEAD)) * NPAD + np] = h;
          }
        }
      }
  } else {  // MODE_ARGMAX
    float vv[4][4]; int ii[4][4];
    #pragma unroll
    for (int mi = 0; mi < 4; ++mi)
      #pragma unroll
      for (int r = 0; r < 4; ++r) {
        float v = -FLT_MAX; int vi = 0x7fffffff;
        #pragma unroll
        for (int ni = 0; ni < 4; ++ni) {
          int col = n0 + wc * 64 + ni * 16 + l15;
          float s = (col < NMEM) ? acc[mi][ni][r] : -FLT_MAX;
          if (s > v) { v = s; vi = col; }
        }
        #pragma unroll
        for (int off = 1; off < 16; off <<= 1) {
          float ov = __shfl_xor(v, off);
          int   oi = __shfl_xor(vi, off);
          if (ov > v || (ov == v && oi < vi)) { v = ov; vi = oi; }
        }
        vv[mi][r] = v; ii[mi][r] = vi;
        if (wc == 0 && l15 == 0) {
          int lrow = wr * 64 + mi * 16 + g * 4 + r;
          s_pv[lrow] = v; s_pi[lrow] = vi;
        }
      }
    __syncthreads();
    if (wc == 1 && l15 == 0) {
      #pragma unroll
      for (int mi = 0; mi < 4; ++mi)
        #pragma unroll
        for (int r = 0; r < 4; ++r) {
          int lrow = wr * 64 + mi * 16 + g * 4 + r;
          float v0 = s_pv[lrow]; int i0 = s_pi[lrow];
          float v1 = vv[mi][r];  int i1 = ii[mi][r];
          float v; int vi;
          if (v1 > v0) { v = v1; vi = i1; } else { v = v0; vi = i0; }
          pv[(size_t)blockIdx.y * ROWS + m0 + lrow] = v;
          pi[(size_t)blockIdx.y * ROWS + m0 + lrow] = vi;
        }
    }
  }
}

__global__ __launch_bounds__(256) void knn_reduce(const float* __restrict__ pv,
                                                  const int* __restrict__ pi,
                                                  int* __restrict__ idx) {
  int r = blockIdx.x * 256 + threadIdx.x;
  float bv = -FLT_MAX; int bi = 0x7fffffff;
  #pragma unroll
  for (int c = 0; c < 8; ++c) {
    float v = pv[(size_t)c * ROWS + r];
    int   i = pi[(size_t)c * ROWS + r];
    if (v > bv || (v == bv && i < bi)) { bv = v; bi = i; }
  }
  idx[r] = bi;
}

// ---------------------------------------------------------------------------
// Per-batch histogram of idx -> log2(count) bias (masked slots = -1e30).
// ---------------------------------------------------------------------------
__global__ __launch_bounds__(256) void hist_lc(const int* __restrict__ idx,
                                               float* __restrict__ lc) {
  __shared__ int hcnt[NPAD];
  const int t = threadIdx.x, b = blockIdx.x;
  #pragma unroll
  for (int i = 0; i < 4; ++i) hcnt[t + 256 * i] = 0;
  __syncthreads();
  #pragma unroll
  for (int i = 0; i < 8; ++i) atomicAdd(&hcnt[idx[b * SEQ + i * 256 + t]], 1);
  __syncthreads();
  #pragma unroll
  for (int i = 0; i < 4; ++i) {
    int n = t + 256 * i;
    int c = hcnt[n];
    lc[b * NPAD + n] = (n < NMEM && c > 0) ? log2f((float)c) : -1e30f;
  }
}

// ---------------------------------------------------------------------------
// Attention over the 1000-entry table, exp2-domain static softmax.
// BARRIER-FREE: K/V fragments read directly from L2 (tables are 256KB/batch,
// L2-resident); only per-wave P goes through LDS (packed 8B stores, key
// columns permuted to match VtT's n' permutation).
// ---------------------------------------------------------------------------
__global__ __launch_bounds__(256) void attn_table(const __bf16* __restrict__ qph,
                                                  const __bf16* __restrict__ Ktab,
                                                  const __bf16* __restrict__ VtTp,
                                                  const float* __restrict__ lc2,
                                                  __bf16* __restrict__ attn_bf) {
  __shared__ __bf16 sP[4][32][72];   // per-wave P, permuted key cols [0,64)
  const int t = threadIdx.x;
  const int wq = t >> 6, lane = t & 63, l15 = lane & 15, g = lane >> 4;
  const int b = blockIdx.z, h = blockIdx.y;
  const int q0 = blockIdx.x * 128 + wq * 32;

  bf16x8 qa[2][2];
  #pragma unroll
  for (int mi = 0; mi < 2; ++mi)
    #pragma unroll
    for (int ks = 0; ks < 2; ++ks)
      qa[mi][ks] = *(const bf16x8*)&qph[(size_t)(b * SEQ + q0 + mi * 16 + l15) * DIM +
                                        h * DHEAD + ks * 32 + g * 8];

  f32x4 O[2][4];
  #pragma unroll
  for (int mi = 0; mi < 2; ++mi)
    #pragma unroll
    for (int fd = 0; fd < 4; ++fd) O[mi][fd] = (f32x4){0.f, 0.f, 0.f, 0.f};
  float lsum[2][4];
  #pragma unroll
  for (int mi = 0; mi < 2; ++mi)
    #pragma unroll
    for (int r = 0; r < 4; ++r) lsum[mi][r] = 0.f;

  const __bf16* Kb = Ktab + (size_t)b * NPAD * DHEAD;
  const __bf16* Vb = VtTp + (size_t)b * DHEAD * NPAD;
  const float* lcb = lc2 + b * NPAD;

  for (int n0 = 0; n0 < NPAD; n0 += 64) {
    float lcv[4];
    #pragma unroll
    for (int ni = 0; ni < 4; ++ni) lcv[ni] = lcb[n0 + ni * 16 + l15];

    // S = Q K^T, K fragments straight from L2 (row-major Ktab, 16B loads)
    f32x4 S[2][4];
    #pragma unroll
    for (int mi = 0; mi < 2; ++mi)
      #pragma unroll
      for (int ni = 0; ni < 4; ++ni) S[mi][ni] = (f32x4){0.f, 0.f, 0.f, 0.f};
    #pragma unroll
    for (int ks = 0; ks < 2; ++ks) {
      bf16x8 kf[4];
      #pragma unroll
      for (int ni = 0; ni < 4; ++ni)
        kf[ni] = *(const bf16x8*)&Kb[(size_t)(n0 + ni * 16 + l15) * DHEAD + ks * 32 + g * 8];
      #pragma unroll
      for (int mi = 0; mi < 2; ++mi)
        #pragma unroll
        for (int ni = 0; ni < 4; ++ni)
          S[mi][ni] = mfma16(qa[mi][ks], kf[ni], S[mi][ni]);
    }

    // p = exp2(S + log2 c); packed P store at permuted col' = l15*4 + ni
    #pragma unroll
    for (int mi = 0; mi < 2; ++mi)
      #pragma unroll
      for (int r = 0; r < 4; ++r) {
        int row = mi * 16 + g * 4 + r;
        bf16x4 p4;
        float rs = 0.f;
        #pragma unroll
        for (int ni = 0; ni < 4; ++ni) {
          float p = __builtin_amdgcn_exp2f(S[mi][ni][r] + lcv[ni]);
          rs += p;
          p4[ni] = (__bf16)p;
        }
        *(bf16x4*)&sP[wq][row][l15 * 4] = p4;
        lsum[mi][r] += rs;
      }

    // O += P V, V fragments straight from L2 (VtTp rows contiguous in n')
    #pragma unroll
    for (int ks = 0; ks < 2; ++ks) {
      bf16x8 vf[4];
      #pragma unroll
      for (int fd = 0; fd < 4; ++fd)
        vf[fd] = *(const bf16x8*)&Vb[(size_t)(fd * 16 + l15) * NPAD + n0 + ks * 32 + g * 8];
      #pragma unroll
      for (int mi = 0; mi < 2; ++mi) {
        bf16x8 pa = *(const bf16x8*)&sP[wq][mi * 16 + l15][ks * 32 + g * 8];
        #pragma unroll
        for (int fd = 0; fd < 4; ++fd)
          O[mi][fd] = mfma16(pa, vf[fd], O[mi][fd]);
      }
    }
  }

  #pragma unroll
  for (int mi = 0; mi < 2; ++mi)
    #pragma unroll
    for (int r = 0; r < 4; ++r) {
      float rs = lsum[mi][r];
      #pragma unroll
      for (int off = 1; off < 16; off <<= 1) rs += __shfl_xor(rs, off);
      float inv = 1.f / rs;
      size_t row = (size_t)(b * SEQ + q0 + mi * 16 + g * 4 + r);
      #pragma unroll
      for (int fd = 0; fd < 4; ++fd)
        attn_bf[row * DIM + h * DHEAD + fd * 16 + l15] = (__bf16)(O[mi][fd][r] * inv);
    }
}

// ---------------------------------------------------------------------------
// Casts
// ---------------------------------------------------------------------------
__global__ __launch_bounds__(256) void cast_w_t(const float* __restrict__ in,
                                                __bf16* __restrict__ oh,
                                                __bf16* __restrict__ ol,
                                                int writeLo) {
  __shared__ float tile[64][65];
  const int t = threadIdx.x;
  const int k0 = blockIdx.x * 64, n0 = blockIdx.y * 64;
  #pragma unroll
  for (int i = 0; i < 16; ++i) {
    int e = t + i * 256, r = e >> 6, c = e & 63;
    tile[r][c] = in[(size_t)(k0 + r) * DIM + n0 + c];
  }
  __syncthreads();
  #pragma unroll
  for (int i = 0; i < 16; ++i) {
    int e = t + i * 256, r = e >> 6, c = e & 63;
    float v = tile[c][r];
    __bf16 h = (__bf16)v;
    oh[(size_t)(n0 + r) * DIM + k0 + c] = h;
    if (writeLo) ol[(size_t)(n0 + r) * DIM + k0 + c] = (__bf16)(v - (float)h);
  }
}

// w_kv [1024][128] f32 -> [128][1024] bf16 hi/lo
__global__ __launch_bounds__(256) void cast_wkv_t(const float* __restrict__ in,
                                                  __bf16* __restrict__ oh,
                                                  __bf16* __restrict__ ol) {
  __shared__ float tile[64][65];
  const int t = threadIdx.x;
  const int k0 = blockIdx.x * 64, n0 = blockIdx.y * 64;
  #pragma unroll
  for (int i = 0; i < 16; ++i) {
    int e = t + i * 256, r = e >> 6, c = e & 63;
    tile[r][c] = in[(size_t)(k0 + r) * 128 + n0 + c];
  }
  __syncthreads();
  #pragma unroll
  for (int i = 0; i < 16; ++i) {
    int e = t + i * 256, r = e >> 6, c = e & 63;
    float v = tile[c][r];
    __bf16 h = (__bf16)v;
    oh[(size_t)(n0 + r) * DIM + k0 + c] = h;
    ol[(size_t)(n0 + r) * DIM + k0 + c] = (__bf16)(v - (float)h);
  }
}

__global__ __launch_bounds__(256) void cast_mem(const float* __restrict__ mem,
                                                __bf16* __restrict__ mh,
                                                __bf16* __restrict__ ml) {
  size_t e = ((size_t)blockIdx.x * 256 + threadIdx.x) * 8;
  int d = (int)(e & 1023);
  size_t rn = e >> 10;
  int n = (int)(rn & 1023), b = (int)(rn >> 10);
  bf16x8 h8, l8;
  if (n < NMEM) {
    const float* p = mem + ((size_t)b * NMEM + n) * DIM + d;
    #pragma unroll
    for (int j = 0; j < 8; ++j) {
      float v = p[j];
      __bf16 h = (__bf16)v;
      h8[j] = h; l8[j] = (__bf16)(v - (float)h);
    }
  } else {
    #pragma unroll
    for (int j = 0; j < 8; ++j) { h8[j] = (__bf16)0.f; l8[j] = (__bf16)0.f; }
  }
  *(bf16x8*)(mh + e) = h8;
  *(bf16x8*)(ml + e) = l8;
}

// ---------------------------------------------------------------------------
extern "C" void kernel_launch(void* const* d_in, const int* in_sizes, int n_in,
                              void* d_out, int out_size, void* d_ws, size_t ws_size,
                              hipStream_t stream) {
  const float* q        = (const float*)d_in[0];
  const float* mem      = (const float*)d_in[2];
  const float* w_q      = (const float*)d_in[3];
  const float* w_kv     = (const float*)d_in[4];
  const float* w_concat = (const float*)d_in[5];
  float* out = (float*)d_out;

  char* wsb = (char*)d_ws;
  __bf16* memh   = (__bf16*)(wsb + 0);                  //  8 MiB
  __bf16* meml   = (__bf16*)(wsb + 8388608);            //  8 MiB
  __bf16* wqt_h  = (__bf16*)(wsb + 16777216);           //  2 MiB
  __bf16* wqt_l  = (__bf16*)(wsb + 18874368);           //  2 MiB
  __bf16* wct    = (__bf16*)(wsb + 20971520);           //  2 MiB
  __bf16* Ktab   = (__bf16*)(wsb + 23068672);           //  512 KiB
  __bf16* VtT    = (__bf16*)(wsb + 23592960);           //  512 KiB
  float*  lc     = (float*) (wsb + 24117248);           //  16 KiB
  float*  pv     = (float*) (wsb + 24133632);           //  256 KiB
  int*    pi     = (int*)   (wsb + 24395776);           //  256 KiB
  int*    idx    = (int*)   (wsb + 24657920);           //  32 KiB
  __bf16* wkvT_h = (__bf16*)(wsb + 24690688);           //  256 KiB
  __bf16* wkvT_l = (__bf16*)(wsb + 24952832);           //  256 KiB
  __bf16* qph    = (__bf16*)(wsb + 25214976);           // 16 MiB
  __bf16* qpl    = (__bf16*)(wsb + 41992192);           // 16 MiB (reused as attn_bf)
  __bf16* attn_bf = qpl;

  cast_w_t<<<dim3(16, 16), 256, 0, stream>>>(w_q, wqt_h, wqt_l, 1);
  cast_w_t<<<dim3(16, 16), 256, 0, stream>>>(w_concat, wct, (__bf16*)0, 0);
  cast_wkv_t<<<dim3(16, 2), 256, 0, stream>>>(w_kv, wkvT_h, wkvT_l);
  cast_mem<<<dim3(2048), 256, 0, stream>>>(mem, memh, meml);

  // qp = q @ w_q, pre-scaled by QSCALE -> qph/qpl
  gemm3<1, 3, MODE_HILO><<<dim3(64, 8, 1), 256, 32768, stream>>>(
      (const void*)q, (const __bf16*)0, wqt_h, wqt_l, 0, 0,
      (float*)0, qph, qpl, (float*)0, (int*)0);

  // K/V tables over all memories: (memh/meml) @ w_kv^T -> Ktab, VtT (permuted)
  gemm3<0, 3, MODE_KV><<<dim3(BATCH * NPAD / 128, 1, 1), 256, 32768, stream>>>(
      (const void*)memh, meml, wkvT_h, wkvT_l, 0, 0,
      (float*)0, Ktab, VtT, (float*)0, (int*)0);

  // kNN scores + argmax partials (scores scaled by QSCALE: argmax-invariant)
  gemm3<0, 3, MODE_ARGMAX><<<dim3(16, 8, 4), 256, 32768, stream>>>(
      (const void*)qph, qpl, memh, meml, 2048, (long)NPAD * DIM,
      (float*)0, (__bf16*)0, (__bf16*)0, pv, pi);
  knn_reduce<<<dim3(32), 256, 0, stream>>>(pv, pi, idx);

  // counts -> log2 bias
  hist_lc<<<dim3(BATCH), 256, 0, stream>>>(idx, lc);

  // attention over the table (barrier-free)
  attn_table<<<dim3(SEQ / 128, NHEAD, BATCH), 256, 0, stream>>>(qph, Ktab, VtT, lc, attn_bf);

  // out = attn @ w_concat
  gemm3<0, 1, MODE_C><<<dim3(64, 8, 1), 256, 16384, stream>>>(
      (const void*)attn_bf, (const __bf16*)0, wct, (const __bf16*)0, 0, 0,
      out, (__bf16*)0, (__bf16*)0, (float*)0, (int*)0);
}

// Round 7
// 257.245 us; speedup vs baseline: 1.3628x; 1.3628x over previous
//
#include <hip/hip_runtime.h>
#include <float.h>
#include <math.h>

// KNNAttention: b=4, l=2048, d=1024, h=16, dh=64, n_mem=1000
#define BATCH 4
#define SEQ   2048
#define DIM   1024
#define NHEAD 16
#define DHEAD 64
#define NMEM  1000
#define NPAD  1024          // padded memory slots
#define ROWS  (BATCH*SEQ)   // 8192
// qp pre-scale: 0.125 * log2(e); softmax becomes exp2(S + log2(count))
#define QSCALE 0.18033688011112042f

typedef __attribute__((ext_vector_type(8))) __bf16 bf16x8;
typedef __attribute__((ext_vector_type(4))) __bf16 bf16x4;
typedef __attribute__((ext_vector_type(4))) float  f32x4;

static __device__ inline f32x4 mfma16(bf16x8 a, bf16x8 b, f32x4 c) {
  return __builtin_amdgcn_mfma_f32_16x16x32_bf16(a, b, c, 0, 0, 0);
}

// async global->LDS, 16B per lane. LDS dest must be wave-uniform base (+lane*16).
#define GLOAD16(g, l) __builtin_amdgcn_global_load_lds( \
    (const __attribute__((address_space(1))) unsigned int*)(g), \
    (__attribute__((address_space(3))) unsigned int*)(l), 16, 0, 0)

enum { MODE_C = 0, MODE_HILO = 1, MODE_ARGMAX = 2, MODE_KV = 3 };

// ---------------------------------------------------------------------------
// Fused split-bf16 GEMM (verified rounds 2-6): C = A * B^T, up to 3 products.
// ---------------------------------------------------------------------------
template<int AF32, int NPROD, int MODE>
__global__ __launch_bounds__(256) void gemm3(
    const void* __restrict__ Ah_, const __bf16* __restrict__ Al,
    const __bf16* __restrict__ Bh, const __bf16* __restrict__ Bl,
    int rowsPerZ, long bStrideZ,
    float* __restrict__ C, __bf16* __restrict__ Oh, __bf16* __restrict__ Ol,
    float* __restrict__ pv, int* __restrict__ pi)
{
  extern __shared__ char smem[];
  __shared__ float s_pv[128];
  __shared__ int   s_pi[128];
  const int t = threadIdx.x;
  const int w = t >> 6, lane = t & 63, l15 = lane & 15, g = lane >> 4;
  const int wr = w >> 1, wc = w & 1;
  const int m0 = blockIdx.z * rowsPerZ + blockIdx.x * 128;
  const int n0 = blockIdx.y * 128;
  const __bf16* Bh_b = Bh + (size_t)blockIdx.z * bStrideZ;
  const __bf16* Bl_b = (NPROD == 3) ? (Bl + (size_t)blockIdx.z * bStrideZ) : (const __bf16*)0;

  char* sA  = smem;
  char* sAl = smem + 8192;
  char* sBh = smem + (AF32 ? 16384 : (NPROD == 3 ? 16384 : 8192));
  char* sBl = sBh + 8192;

  f32x4 acc[4][4];
  #pragma unroll
  for (int i = 0; i < 4; ++i)
    #pragma unroll
    for (int j = 0; j < 4; ++j) acc[i][j] = (f32x4){0.f, 0.f, 0.f, 0.f};

  for (int k0 = 0; k0 < DIM; k0 += 32) {
    if (AF32) {
      const float* Af = (const float*)Ah_;
      #pragma unroll
      for (int i = 0; i < 4; ++i) {
        int c = i * 256 + t;
        int r = c >> 3, s = c & 7;
        int sl = s ^ (r & 7);
        GLOAD16(&Af[(size_t)(m0 + r) * DIM + k0 + sl * 4], sA + i * 4096 + w * 1024);
      }
    } else {
      const __bf16* Ab = (const __bf16*)Ah_;
      #pragma unroll
      for (int i = 0; i < 2; ++i) {
        int c = i * 256 + t;
        int r = c >> 2, s = c & 3;
        int sl = s ^ (r & 3);
        GLOAD16(&Ab[(size_t)(m0 + r) * DIM + k0 + sl * 8], sA + i * 4096 + w * 1024);
        if (NPROD == 3)
          GLOAD16(&Al[(size_t)(m0 + r) * DIM + k0 + sl * 8], sAl + i * 4096 + w * 1024);
      }
    }
    #pragma unroll
    for (int i = 0; i < 2; ++i) {
      int c = i * 256 + t;
      int r = c >> 2, s = c & 3;
      int sl = s ^ (r & 3);
      GLOAD16(&Bh_b[(size_t)(n0 + r) * DIM + k0 + sl * 8], sBh + i * 4096 + w * 1024);
      if (NPROD == 3)
        GLOAD16(&Bl_b[(size_t)(n0 + r) * DIM + k0 + sl * 8], sBl + i * 4096 + w * 1024);
    }
    __syncthreads();

    bf16x8 ah[4], al[4], bh[4], bl[4];
    #pragma unroll
    for (int mi = 0; mi < 4; ++mi) {
      int r = wr * 64 + mi * 16 + l15;
      if (AF32) {
        int p0 = (2 * g) ^ (r & 7), p1 = (2 * g + 1) ^ (r & 7);
        float4 q0 = *(const float4*)(sA + r * 128 + p0 * 16);
        float4 q1 = *(const float4*)(sA + r * 128 + p1 * 16);
        float qq[8] = {q0.x, q0.y, q0.z, q0.w, q1.x, q1.y, q1.z, q1.w};
        #pragma unroll
        for (int j = 0; j < 8; ++j) {
          __bf16 h = (__bf16)qq[j];
          ah[mi][j] = h;
          al[mi][j] = (__bf16)(qq[j] - (float)h);
        }
      } else {
        int p = (g ^ (r & 3)) * 16;
        ah[mi] = *(const bf16x8*)(sA + r * 64 + p);
        if (NPROD == 3) al[mi] = *(const bf16x8*)(sAl + r * 64 + p);
      }
    }
    #pragma unroll
    for (int ni = 0; ni < 4; ++ni) {
      int r = wc * 64 + ni * 16 + l15;
      int p = (g ^ (r & 3)) * 16;
      bh[ni] = *(const bf16x8*)(sBh + r * 64 + p);
      if (NPROD == 3) bl[ni] = *(const bf16x8*)(sBl + r * 64 + p);
    }
    #pragma unroll
    for (int mi = 0; mi < 4; ++mi)
      #pragma unroll
      for (int ni = 0; ni < 4; ++ni) {
        acc[mi][ni] = mfma16(ah[mi], bh[ni], acc[mi][ni]);
        if (NPROD == 3) {
          acc[mi][ni] = mfma16(ah[mi], bl[ni], acc[mi][ni]);
          acc[mi][ni] = mfma16(al[mi], bh[ni], acc[mi][ni]);
        }
      }
    __syncthreads();
  }

  if (MODE == MODE_C) {
    #pragma unroll
    for (int mi = 0; mi < 4; ++mi)
      #pragma unroll
      for (int ni = 0; ni < 4; ++ni) {
        int col = n0 + wc * 64 + ni * 16 + l15;
        #pragma unroll
        for (int r = 0; r < 4; ++r) {
          int row = m0 + wr * 64 + mi * 16 + g * 4 + r;
          C[(size_t)row * DIM + col] = acc[mi][ni][r];
        }
      }
  } else if (MODE == MODE_HILO) {
    #pragma unroll
    for (int mi = 0; mi < 4; ++mi)
      #pragma unroll
      for (int ni = 0; ni < 4; ++ni) {
        int col = n0 + wc * 64 + ni * 16 + l15;
        #pragma unroll
        for (int r = 0; r < 4; ++r) {
          int row = m0 + wr * 64 + mi * 16 + g * 4 + r;
          float v = acc[mi][ni][r] * QSCALE;
          __bf16 h = (__bf16)v;
          Oh[(size_t)row * DIM + col] = h;
          Ol[(size_t)row * DIM + col] = (__bf16)(v - (float)h);
        }
      }
  } else if (MODE == MODE_KV) {
    // Oh = Ktab [b*NPAD+n][64], Ol = VtT [b][64][NPAD] at permuted n'
    #pragma unroll
    for (int mi = 0; mi < 4; ++mi)
      #pragma unroll
      for (int ni = 0; ni < 4; ++ni) {
        int col = wc * 64 + ni * 16 + l15;
        #pragma unroll
        for (int r = 0; r < 4; ++r) {
          int gr = m0 + wr * 64 + mi * 16 + g * 4 + r;
          int bb = gr >> 10, n = gr & (NPAD - 1);
          __bf16 h = (__bf16)acc[mi][ni][r];
          if (col < DHEAD) {
            Oh[(size_t)gr * DHEAD + col] = h;
          } else {
            int np = (n & ~63) | ((n & 15) << 2) | ((n >> 4) & 3);
            Ol[((size_t)bb * DHEAD + (col - DHEAD)) * NPAD + np] = h;
          }
        }
      }
  } else {  // MODE_ARGMAX
    float vv[4][4]; int ii[4][4];
    #pragma unroll
    for (int mi = 0; mi < 4; ++mi)
      #pragma unroll
      for (int r = 0; r < 4; ++r) {
        float v = -FLT_MAX; int vi = 0x7fffffff;
        #pragma unroll
        for (int ni = 0; ni < 4; ++ni) {
          int col = n0 + wc * 64 + ni * 16 + l15;
          float s = (col < NMEM) ? acc[mi][ni][r] : -FLT_MAX;
          if (s > v) { v = s; vi = col; }
        }
        #pragma unroll
        for (int off = 1; off < 16; off <<= 1) {
          float ov = __shfl_xor(v, off);
          int   oi = __shfl_xor(vi, off);
          if (ov > v || (ov == v && oi < vi)) { v = ov; vi = oi; }
        }
        vv[mi][r] = v; ii[mi][r] = vi;
        if (wc == 0 && l15 == 0) {
          int lrow = wr * 64 + mi * 16 + g * 4 + r;
          s_pv[lrow] = v; s_pi[lrow] = vi;
        }
      }
    __syncthreads();
    if (wc == 1 && l15 == 0) {
      #pragma unroll
      for (int mi = 0; mi < 4; ++mi)
        #pragma unroll
        for (int r = 0; r < 4; ++r) {
          int lrow = wr * 64 + mi * 16 + g * 4 + r;
          float v0 = s_pv[lrow]; int i0 = s_pi[lrow];
          float v1 = vv[mi][r];  int i1 = ii[mi][r];
          float v; int vi;
          if (v1 > v0) { v = v1; vi = i1; } else { v = v0; vi = i0; }
          pv[(size_t)blockIdx.y * ROWS + m0 + lrow] = v;
          pi[(size_t)blockIdx.y * ROWS + m0 + lrow] = vi;
        }
    }
  }
}

__global__ __launch_bounds__(256) void knn_reduce(const float* __restrict__ pv,
                                                  const int* __restrict__ pi,
                                                  int* __restrict__ idx) {
  int r = blockIdx.x * 256 + threadIdx.x;
  float bv = -FLT_MAX; int bi = 0x7fffffff;
  #pragma unroll
  for (int c = 0; c < 8; ++c) {
    float v = pv[(size_t)c * ROWS + r];
    int   i = pi[(size_t)c * ROWS + r];
    if (v > bv || (v == bv && i < bi)) { bv = v; bi = i; }
  }
  idx[r] = bi;
}

// ---------------------------------------------------------------------------
// Per-batch histogram of idx -> log2(count) bias (masked slots = -1e30).
// ---------------------------------------------------------------------------
__global__ __launch_bounds__(256) void hist_lc(const int* __restrict__ idx,
                                               float* __restrict__ lc) {
  __shared__ int hcnt[NPAD];
  const int t = threadIdx.x, b = blockIdx.x;
  #pragma unroll
  for (int i = 0; i < 4; ++i) hcnt[t + 256 * i] = 0;
  __syncthreads();
  #pragma unroll
  for (int i = 0; i < 8; ++i) atomicAdd(&hcnt[idx[b * SEQ + i * 256 + t]], 1);
  __syncthreads();
  #pragma unroll
  for (int i = 0; i < 4; ++i) {
    int n = t + 256 * i;
    int c = hcnt[n];
    lc[b * NPAD + n] = (n < NMEM && c > 0) ? log2f((float)c) : -1e30f;
  }
}

// ---------------------------------------------------------------------------
// Attention over the 1000-entry table, exp2 static softmax.
// LDS-staged K/V with DOUBLE BUFFERING (issue next-tile global_load_lds before
// computing current tile; one barrier per tile -> L2 latency hides under 64
// MFMAs + softmax). 4 waves x 64 q-rows = 256 rows/block, grid (8,16,4).
// sP: per-wave, stride 64 + XOR bank swizzle. Total LDS = 64 KiB.
// ---------------------------------------------------------------------------
__global__ __launch_bounds__(256) void attn_table(const __bf16* __restrict__ qph,
                                                  const __bf16* __restrict__ Ktab,
                                                  const __bf16* __restrict__ VtTp,
                                                  const float* __restrict__ lc2,
                                                  __bf16* __restrict__ attn_bf) {
  extern __shared__ char smem[];
  char* sK = smem;                 // [2][8192]: K tiles [64 key][64 d]
  char* sV = smem + 16384;         // [2][8192]: V^T tiles [64 d][64 key']
  char* sP = smem + 32768;         // [4 waves][64 rows][64 keys'], XOR-swizzled

  const int t = threadIdx.x;
  const int wq = t >> 6, lane = t & 63, l15 = lane & 15, g = lane >> 4;
  const int b = blockIdx.z, h = blockIdx.y;
  const int q0 = blockIdx.x * 256 + wq * 64;

  // Q fragments: 4 row-blocks x 2 k-steps
  bf16x8 qa[4][2];
  #pragma unroll
  for (int mi = 0; mi < 4; ++mi)
    #pragma unroll
    for (int ks = 0; ks < 2; ++ks)
      qa[mi][ks] = *(const bf16x8*)&qph[(size_t)(b * SEQ + q0 + mi * 16 + l15) * DIM +
                                        h * DHEAD + ks * 32 + g * 8];

  f32x4 O[4][4];
  #pragma unroll
  for (int mi = 0; mi < 4; ++mi)
    #pragma unroll
    for (int fd = 0; fd < 4; ++fd) O[mi][fd] = (f32x4){0.f, 0.f, 0.f, 0.f};
  float lsum[4][4];
  #pragma unroll
  for (int mi = 0; mi < 4; ++mi)
    #pragma unroll
    for (int r = 0; r < 4; ++r) lsum[mi][r] = 0.f;

  const __bf16* Kb = Ktab + (size_t)b * NPAD * DHEAD;
  const __bf16* Vb = VtTp + (size_t)b * DHEAD * NPAD;
  const float* lcb = lc2 + b * NPAD;
  char* sPw = sP + wq * 8192;

  // stage tile `tile` into buffer `buf` (linear LDS dest, pre-swizzled source)
  auto STAGE = [&](int buf, int tile) {
    const int n0 = tile * 64;
    #pragma unroll
    for (int i = 0; i < 2; ++i) {
      int c = i * 256 + t, row = c >> 3, s = c & 7, sl = s ^ (row & 7);
      GLOAD16(&Kb[(size_t)(n0 + row) * DHEAD + sl * 8], sK + buf * 8192 + i * 4096 + wq * 1024);
      GLOAD16(&Vb[(size_t)row * NPAD + n0 + sl * 8], sV + buf * 8192 + i * 4096 + wq * 1024);
    }
  };

  STAGE(0, 0);
  __syncthreads();
  int cur = 0;

  for (int tile = 0; tile < NPAD / 64; ++tile) {
    if (tile + 1 < NPAD / 64) STAGE(cur ^ 1, tile + 1);  // prefetch next

    const int n0 = tile * 64;
    float lcv[4];
    #pragma unroll
    for (int ni = 0; ni < 4; ++ni) lcv[ni] = lcb[n0 + ni * 16 + l15];

    // K fragments for the whole tile (8 ds_read_b128)
    bf16x8 kf[2][4];
    #pragma unroll
    for (int ks = 0; ks < 2; ++ks)
      #pragma unroll
      for (int ni = 0; ni < 4; ++ni)
        kf[ks][ni] = *(const bf16x8*)(sK + cur * 8192 + (ni * 16 + l15) * 128 +
                                      (((ks * 4 + g) ^ (l15 & 7)) * 16));

    // per-mi: QK -> softmax -> packed P store (S lifetime = 1 mi)
    #pragma unroll
    for (int mi = 0; mi < 4; ++mi) {
      f32x4 S[4];
      #pragma unroll
      for (int ni = 0; ni < 4; ++ni) S[ni] = (f32x4){0.f, 0.f, 0.f, 0.f};
      __builtin_amdgcn_s_setprio(1);
      #pragma unroll
      for (int ks = 0; ks < 2; ++ks)
        #pragma unroll
        for (int ni = 0; ni < 4; ++ni)
          S[ni] = mfma16(qa[mi][ks], kf[ks][ni], S[ni]);
      __builtin_amdgcn_s_setprio(0);
      #pragma unroll
      for (int r = 0; r < 4; ++r) {
        int row = mi * 16 + g * 4 + r;
        bf16x4 p4;
        float rs = 0.f;
        #pragma unroll
        for (int ni = 0; ni < 4; ++ni) {
          float p = __builtin_amdgcn_exp2f(S[ni][r] + lcv[ni]);
          rs += p;
          p4[ni] = (__bf16)p;
        }
        // packed 8B store at swizzled offset (col' = l15*4 + ni)
        *(bf16x4*)(sPw + row * 128 + ((l15 * 8) ^ ((row & 7) << 4))) = p4;
        lsum[mi][r] += rs;
      }
    }

    // O += P V (sP same-wave; V from staged tile)
    #pragma unroll
    for (int ks = 0; ks < 2; ++ks) {
      bf16x8 vf[4];
      #pragma unroll
      for (int fd = 0; fd < 4; ++fd)
        vf[fd] = *(const bf16x8*)(sV + cur * 8192 + (fd * 16 + l15) * 128 +
                                  (((ks * 4 + g) ^ (l15 & 7)) * 16));
      __builtin_amdgcn_s_setprio(1);
      #pragma unroll
      for (int mi = 0; mi < 4; ++mi) {
        int row = mi * 16 + l15;
        bf16x8 pa = *(const bf16x8*)(sPw + row * 128 +
                                     ((ks * 64 + g * 16) ^ ((row & 7) << 4)));
        #pragma unroll
        for (int fd = 0; fd < 4; ++fd)
          O[mi][fd] = mfma16(pa, vf[fd], O[mi][fd]);
      }
      __builtin_amdgcn_s_setprio(0);
    }

    __syncthreads();   // drains prefetch vmcnt; all waves done with buf[cur]
    cur ^= 1;
  }

  #pragma unroll
  for (int mi = 0; mi < 4; ++mi)
    #pragma unroll
    for (int r = 0; r < 4; ++r) {
      float rs = lsum[mi][r];
      #pragma unroll
      for (int off = 1; off < 16; off <<= 1) rs += __shfl_xor(rs, off);
      float inv = 1.f / rs;
      size_t row = (size_t)(b * SEQ + q0 + mi * 16 + g * 4 + r);
      #pragma unroll
      for (int fd = 0; fd < 4; ++fd)
        attn_bf[row * DIM + h * DHEAD + fd * 16 + l15] = (__bf16)(O[mi][fd][r] * inv);
    }
}

// ---------------------------------------------------------------------------
// Casts
// ---------------------------------------------------------------------------
__global__ __launch_bounds__(256) void cast_w_t(const float* __restrict__ in,
                                                __bf16* __restrict__ oh,
                                                __bf16* __restrict__ ol,
                                                int writeLo) {
  __shared__ float tile[64][65];
  const int t = threadIdx.x;
  const int k0 = blockIdx.x * 64, n0 = blockIdx.y * 64;
  #pragma unroll
  for (int i = 0; i < 16; ++i) {
    int e = t + i * 256, r = e >> 6, c = e & 63;
    tile[r][c] = in[(size_t)(k0 + r) * DIM + n0 + c];
  }
  __syncthreads();
  #pragma unroll
  for (int i = 0; i < 16; ++i) {
    int e = t + i * 256, r = e >> 6, c = e & 63;
    float v = tile[c][r];
    __bf16 h = (__bf16)v;
    oh[(size_t)(n0 + r) * DIM + k0 + c] = h;
    if (writeLo) ol[(size_t)(n0 + r) * DIM + k0 + c] = (__bf16)(v - (float)h);
  }
}

// w_kv [1024][128] f32 -> [128][1024] bf16 hi/lo
__global__ __launch_bounds__(256) void cast_wkv_t(const float* __restrict__ in,
                                                  __bf16* __restrict__ oh,
                                                  __bf16* __restrict__ ol) {
  __shared__ float tile[64][65];
  const int t = threadIdx.x;
  const int k0 = blockIdx.x * 64, n0 = blockIdx.y * 64;
  #pragma unroll
  for (int i = 0; i < 16; ++i) {
    int e = t + i * 256, r = e >> 6, c = e & 63;
    tile[r][c] = in[(size_t)(k0 + r) * 128 + n0 + c];
  }
  __syncthreads();
  #pragma unroll
  for (int i = 0; i < 16; ++i) {
    int e = t + i * 256, r = e >> 6, c = e & 63;
    float v = tile[c][r];
    __bf16 h = (__bf16)v;
    oh[(size_t)(n0 + r) * DIM + k0 + c] = h;
    ol[(size_t)(n0 + r) * DIM + k0 + c] = (__bf16)(v - (float)h);
  }
}

__global__ __launch_bounds__(256) void cast_mem(const float* __restrict__ mem,
                                                __bf16* __restrict__ mh,
                                                __bf16* __restrict__ ml) {
  size_t e = ((size_t)blockIdx.x * 256 + threadIdx.x) * 8;
  int d = (int)(e & 1023);
  size_t rn = e >> 10;
  int n = (int)(rn & 1023), b = (int)(rn >> 10);
  bf16x8 h8, l8;
  if (n < NMEM) {
    const float* p = mem + ((size_t)b * NMEM + n) * DIM + d;
    #pragma unroll
    for (int j = 0; j < 8; ++j) {
      float v = p[j];
      __bf16 h = (__bf16)v;
      h8[j] = h; l8[j] = (__bf16)(v - (float)h);
    }
  } else {
    #pragma unroll
    for (int j = 0; j < 8; ++j) { h8[j] = (__bf16)0.f; l8[j] = (__bf16)0.f; }
  }
  *(bf16x8*)(mh + e) = h8;
  *(bf16x8*)(ml + e) = l8;
}

// ---------------------------------------------------------------------------
extern "C" void kernel_launch(void* const* d_in, const int* in_sizes, int n_in,
                              void* d_out, int out_size, void* d_ws, size_t ws_size,
                              hipStream_t stream) {
  const float* q        = (const float*)d_in[0];
  const float* mem      = (const float*)d_in[2];
  const float* w_q      = (const float*)d_in[3];
  const float* w_kv     = (const float*)d_in[4];
  const float* w_concat = (const float*)d_in[5];
  float* out = (float*)d_out;

  char* wsb = (char*)d_ws;
  __bf16* memh   = (__bf16*)(wsb + 0);                  //  8 MiB
  __bf16* meml   = (__bf16*)(wsb + 8388608);            //  8 MiB
  __bf16* wqt_h  = (__bf16*)(wsb + 16777216);           //  2 MiB
  __bf16* wqt_l  = (__bf16*)(wsb + 18874368);           //  2 MiB
  __bf16* wct    = (__bf16*)(wsb + 20971520);           //  2 MiB
  __bf16* Ktab   = (__bf16*)(wsb + 23068672);           //  512 KiB
  __bf16* VtT    = (__bf16*)(wsb + 23592960);           //  512 KiB
  float*  lc     = (float*) (wsb + 24117248);           //  16 KiB
  float*  pv     = (float*) (wsb + 24133632);           //  256 KiB
  int*    pi     = (int*)   (wsb + 24395776);           //  256 KiB
  int*    idx    = (int*)   (wsb + 24657920);           //  32 KiB
  __bf16* wkvT_h = (__bf16*)(wsb + 24690688);           //  256 KiB
  __bf16* wkvT_l = (__bf16*)(wsb + 24952832);           //  256 KiB
  __bf16* qph    = (__bf16*)(wsb + 25214976);           // 16 MiB
  __bf16* qpl    = (__bf16*)(wsb + 41992192);           // 16 MiB (reused as attn_bf)
  __bf16* attn_bf = qpl;

  cast_w_t<<<dim3(16, 16), 256, 0, stream>>>(w_q, wqt_h, wqt_l, 1);
  cast_w_t<<<dim3(16, 16), 256, 0, stream>>>(w_concat, wct, (__bf16*)0, 0);
  cast_wkv_t<<<dim3(16, 2), 256, 0, stream>>>(w_kv, wkvT_h, wkvT_l);
  cast_mem<<<dim3(2048), 256, 0, stream>>>(mem, memh, meml);

  // qp = q @ w_q, pre-scaled by QSCALE -> qph/qpl
  gemm3<1, 3, MODE_HILO><<<dim3(64, 8, 1), 256, 32768, stream>>>(
      (const void*)q, (const __bf16*)0, wqt_h, wqt_l, 0, 0,
      (float*)0, qph, qpl, (float*)0, (int*)0);

  // K/V tables over all memories: (memh/meml) @ w_kv^T -> Ktab, VtT (permuted)
  gemm3<0, 3, MODE_KV><<<dim3(BATCH * NPAD / 128, 1, 1), 256, 32768, stream>>>(
      (const void*)memh, meml, wkvT_h, wkvT_l, 0, 0,
      (float*)0, Ktab, VtT, (float*)0, (int*)0);

  // kNN scores + argmax partials (scores scaled by QSCALE: argmax-invariant)
  gemm3<0, 3, MODE_ARGMAX><<<dim3(16, 8, 4), 256, 32768, stream>>>(
      (const void*)qph, qpl, memh, meml, 2048, (long)NPAD * DIM,
      (float*)0, (__bf16*)0, (__bf16*)0, pv, pi);
  knn_reduce<<<dim3(32), 256, 0, stream>>>(pv, pi, idx);

  // counts -> log2 bias
  hist_lc<<<dim3(BATCH), 256, 0, stream>>>(idx, lc);

  // attention over the table (double-buffered staging, 64 KiB LDS)
  attn_table<<<dim3(SEQ / 256, NHEAD, BATCH), 256, 65536, stream>>>(
      qph, Ktab, VtT, lc, attn_bf);

  // out = attn @ w_concat
  gemm3<0, 1, MODE_C><<<dim3(64, 8, 1), 256, 16384, stream>>>(
      (const void*)attn_bf, (const __bf16*)0, wct, (const __bf16*)0, 0, 0,
      out, (__bf16*)0, (__bf16*)0, (float*)0, (int*)0);
}

// Round 8
// 237.185 us; speedup vs baseline: 1.4780x; 1.0846x over previous
//
#include <hip/hip_runtime.h>
#include <float.h>
#include <math.h>

// KNNAttention: b=4, l=2048, d=1024, h=16, dh=64, n_mem=1000
#define BATCH 4
#define SEQ   2048
#define DIM   1024
#define NHEAD 16
#define DHEAD 64
#define NMEM  1000
#define NPAD  1024          // padded memory slots
#define ROWS  (BATCH*SEQ)   // 8192
// qp pre-scale: 0.125 * log2(e); softmax becomes exp2(S + log2(count))
#define QSCALE 0.18033688011112042f

typedef __attribute__((ext_vector_type(8))) __bf16 bf16x8;
typedef __attribute__((ext_vector_type(4))) __bf16 bf16x4;
typedef __attribute__((ext_vector_type(4))) float  f32x4;

static __device__ inline f32x4 mfma16(bf16x8 a, bf16x8 b, f32x4 c) {
  return __builtin_amdgcn_mfma_f32_16x16x32_bf16(a, b, c, 0, 0, 0);
}

// async global->LDS, 16B per lane. LDS dest must be wave-uniform base (+lane*16).
#define GLOAD16(g, l) __builtin_amdgcn_global_load_lds( \
    (const __attribute__((address_space(1))) unsigned int*)(g), \
    (__attribute__((address_space(3))) unsigned int*)(l), 16, 0, 0)

enum { MODE_C = 0, MODE_HILO = 1, MODE_ARGMAX = 2, MODE_KV = 3 };

// ---------------------------------------------------------------------------
// Fused split-bf16 GEMM: C = A * B^T, up to 3 products (Ah*Bh + Ah*Bl + Al*Bh).
// Round 8: T3 2-phase DOUBLE-BUFFERED staging — issue next K-tile's
// global_load_lds before computing the current tile; one barrier per K-step.
// ---------------------------------------------------------------------------
template<int AF32, int NPROD, int MODE>
__global__ __launch_bounds__(256) void gemm3(
    const void* __restrict__ Ah_, const __bf16* __restrict__ Al,
    const __bf16* __restrict__ Bh, const __bf16* __restrict__ Bl,
    int rowsPerZ, long bStrideZ,
    float* __restrict__ C, __bf16* __restrict__ Oh, __bf16* __restrict__ Ol,
    float* __restrict__ pv, int* __restrict__ pi)
{
  extern __shared__ char smem[];
  __shared__ float s_pv[128];
  __shared__ int   s_pi[128];
  const int t = threadIdx.x;
  const int w = t >> 6, lane = t & 63, l15 = lane & 15, g = lane >> 4;
  const int wr = w >> 1, wc = w & 1;
  const int m0 = blockIdx.z * rowsPerZ + blockIdx.x * 128;
  const int n0 = blockIdx.y * 128;
  const __bf16* Bh_b = Bh + (size_t)blockIdx.z * bStrideZ;
  const __bf16* Bl_b = (NPROD == 3) ? (Bl + (size_t)blockIdx.z * bStrideZ) : (const __bf16*)0;

  // single-buffer size: A(16K f32 | 8K bf16 [+8K lo]) + B(8K [+8K lo])
  constexpr int SB = (AF32 || NPROD == 3) ? 32768 : 16384;
  constexpr int BOFF = AF32 ? 16384 : (NPROD == 3 ? 16384 : 8192);

  f32x4 acc[4][4];
  #pragma unroll
  for (int i = 0; i < 4; ++i)
    #pragma unroll
    for (int j = 0; j < 4; ++j) acc[i][j] = (f32x4){0.f, 0.f, 0.f, 0.f};

  // stage K-tile k0 into buffer buf (linear LDS dest, pre-swizzled source)
  auto STAGE = [&](int buf, int k0) {
    char* base = smem + buf * SB;
    if (AF32) {
      const float* Af = (const float*)Ah_;
      #pragma unroll
      for (int i = 0; i < 4; ++i) {
        int c = i * 256 + t;
        int r = c >> 3, s = c & 7;
        int sl = s ^ (r & 7);
        GLOAD16(&Af[(size_t)(m0 + r) * DIM + k0 + sl * 4], base + i * 4096 + w * 1024);
      }
    } else {
      const __bf16* Ab = (const __bf16*)Ah_;
      #pragma unroll
      for (int i = 0; i < 2; ++i) {
        int c = i * 256 + t;
        int r = c >> 2, s = c & 3;
        int sl = s ^ (r & 3);
        GLOAD16(&Ab[(size_t)(m0 + r) * DIM + k0 + sl * 8], base + i * 4096 + w * 1024);
        if (NPROD == 3)
          GLOAD16(&Al[(size_t)(m0 + r) * DIM + k0 + sl * 8], base + 8192 + i * 4096 + w * 1024);
      }
    }
    char* bB = base + BOFF;
    #pragma unroll
    for (int i = 0; i < 2; ++i) {
      int c = i * 256 + t;
      int r = c >> 2, s = c & 3;
      int sl = s ^ (r & 3);
      GLOAD16(&Bh_b[(size_t)(n0 + r) * DIM + k0 + sl * 8], bB + i * 4096 + w * 1024);
      if (NPROD == 3)
        GLOAD16(&Bl_b[(size_t)(n0 + r) * DIM + k0 + sl * 8], bB + 8192 + i * 4096 + w * 1024);
    }
  };

  STAGE(0, 0);
  __syncthreads();             // implicit vmcnt(0): tile 0 resident
  int cur = 0;

  for (int k0 = 0; k0 < DIM; k0 += 32) {
    if (k0 + 32 < DIM) STAGE(cur ^ 1, k0 + 32);   // prefetch next tile

    char* base = smem + cur * SB;
    char* sA   = base;
    char* sAl  = base + 8192;
    char* sBh  = base + BOFF;
    char* sBl  = sBh + 8192;

    bf16x8 ah[4], al[4], bh[4], bl[4];
    #pragma unroll
    for (int mi = 0; mi < 4; ++mi) {
      int r = wr * 64 + mi * 16 + l15;
      if (AF32) {
        int p0 = (2 * g) ^ (r & 7), p1 = (2 * g + 1) ^ (r & 7);
        float4 q0 = *(const float4*)(sA + r * 128 + p0 * 16);
        float4 q1 = *(const float4*)(sA + r * 128 + p1 * 16);
        float qq[8] = {q0.x, q0.y, q0.z, q0.w, q1.x, q1.y, q1.z, q1.w};
        #pragma unroll
        for (int j = 0; j < 8; ++j) {
          __bf16 h = (__bf16)qq[j];
          ah[mi][j] = h;
          al[mi][j] = (__bf16)(qq[j] - (float)h);
        }
      } else {
        int p = (g ^ (r & 3)) * 16;
        ah[mi] = *(const bf16x8*)(sA + r * 64 + p);
        if (NPROD == 3) al[mi] = *(const bf16x8*)(sAl + r * 64 + p);
      }
    }
    #pragma unroll
    for (int ni = 0; ni < 4; ++ni) {
      int r = wc * 64 + ni * 16 + l15;
      int p = (g ^ (r & 3)) * 16;
      bh[ni] = *(const bf16x8*)(sBh + r * 64 + p);
      if (NPROD == 3) bl[ni] = *(const bf16x8*)(sBl + r * 64 + p);
    }
    __builtin_amdgcn_s_setprio(1);
    #pragma unroll
    for (int mi = 0; mi < 4; ++mi)
      #pragma unroll
      for (int ni = 0; ni < 4; ++ni) {
        acc[mi][ni] = mfma16(ah[mi], bh[ni], acc[mi][ni]);
        if (NPROD == 3) {
          acc[mi][ni] = mfma16(ah[mi], bl[ni], acc[mi][ni]);
          acc[mi][ni] = mfma16(al[mi], bh[ni], acc[mi][ni]);
        }
      }
    __builtin_amdgcn_s_setprio(0);
    __syncthreads();          // drains prefetch; all waves done with buf cur
    cur ^= 1;
  }

  if (MODE == MODE_C) {
    #pragma unroll
    for (int mi = 0; mi < 4; ++mi)
      #pragma unroll
      for (int ni = 0; ni < 4; ++ni) {
        int col = n0 + wc * 64 + ni * 16 + l15;
        #pragma unroll
        for (int r = 0; r < 4; ++r) {
          int row = m0 + wr * 64 + mi * 16 + g * 4 + r;
          C[(size_t)row * DIM + col] = acc[mi][ni][r];
        }
      }
  } else if (MODE == MODE_HILO) {
    #pragma unroll
    for (int mi = 0; mi < 4; ++mi)
      #pragma unroll
      for (int ni = 0; ni < 4; ++ni) {
        int col = n0 + wc * 64 + ni * 16 + l15;
        #pragma unroll
        for (int r = 0; r < 4; ++r) {
          int row = m0 + wr * 64 + mi * 16 + g * 4 + r;
          float v = acc[mi][ni][r] * QSCALE;
          __bf16 h = (__bf16)v;
          Oh[(size_t)row * DIM + col] = h;
          Ol[(size_t)row * DIM + col] = (__bf16)(v - (float)h);
        }
      }
  } else if (MODE == MODE_KV) {
    // Oh = Ktab [b*NPAD+n][64], Ol = VtT [b][64][NPAD] at permuted n'
    #pragma unroll
    for (int mi = 0; mi < 4; ++mi)
      #pragma unroll
      for (int ni = 0; ni < 4; ++ni) {
        int col = wc * 64 + ni * 16 + l15;
        #pragma unroll
        for (int r = 0; r < 4; ++r) {
          int gr = m0 + wr * 64 + mi * 16 + g * 4 + r;
          int bb = gr >> 10, n = gr & (NPAD - 1);
          __bf16 h = (__bf16)acc[mi][ni][r];
          if (col < DHEAD) {
            Oh[(size_t)gr * DHEAD + col] = h;
          } else {
            int np = (n & ~63) | ((n & 15) << 2) | ((n >> 4) & 3);
            Ol[((size_t)bb * DHEAD + (col - DHEAD)) * NPAD + np] = h;
          }
        }
      }
  } else {  // MODE_ARGMAX
    float vv[4][4]; int ii[4][4];
    #pragma unroll
    for (int mi = 0; mi < 4; ++mi)
      #pragma unroll
      for (int r = 0; r < 4; ++r) {
        float v = -FLT_MAX; int vi = 0x7fffffff;
        #pragma unroll
        for (int ni = 0; ni < 4; ++ni) {
          int col = n0 + wc * 64 + ni * 16 + l15;
          float s = (col < NMEM) ? acc[mi][ni][r] : -FLT_MAX;
          if (s > v) { v = s; vi = col; }
        }
        #pragma unroll
        for (int off = 1; off < 16; off <<= 1) {
          float ov = __shfl_xor(v, off);
          int   oi = __shfl_xor(vi, off);
          if (ov > v || (ov == v && oi < vi)) { v = ov; vi = oi; }
        }
        vv[mi][r] = v; ii[mi][r] = vi;
        if (wc == 0 && l15 == 0) {
          int lrow = wr * 64 + mi * 16 + g * 4 + r;
          s_pv[lrow] = v; s_pi[lrow] = vi;
        }
      }
    __syncthreads();
    if (wc == 1 && l15 == 0) {
      #pragma unroll
      for (int mi = 0; mi < 4; ++mi)
        #pragma unroll
        for (int r = 0; r < 4; ++r) {
          int lrow = wr * 64 + mi * 16 + g * 4 + r;
          float v0 = s_pv[lrow]; int i0 = s_pi[lrow];
          float v1 = vv[mi][r];  int i1 = ii[mi][r];
          float v; int vi;
          if (v1 > v0) { v = v1; vi = i1; } else { v = v0; vi = i0; }
          pv[(size_t)blockIdx.y * ROWS + m0 + lrow] = v;
          pi[(size_t)blockIdx.y * ROWS + m0 + lrow] = vi;
        }
    }
  }
}

__global__ __launch_bounds__(256) void knn_reduce(const float* __restrict__ pv,
                                                  const int* __restrict__ pi,
                                                  int* __restrict__ idx) {
  int r = blockIdx.x * 256 + threadIdx.x;
  float bv = -FLT_MAX; int bi = 0x7fffffff;
  #pragma unroll
  for (int c = 0; c < 8; ++c) {
    float v = pv[(size_t)c * ROWS + r];
    int   i = pi[(size_t)c * ROWS + r];
    if (v > bv || (v == bv && i < bi)) { bv = v; bi = i; }
  }
  idx[r] = bi;
}

// ---------------------------------------------------------------------------
// Per-batch histogram of idx -> log2(count) bias (masked slots = -1e30).
// ---------------------------------------------------------------------------
__global__ __launch_bounds__(256) void hist_lc(const int* __restrict__ idx,
                                               float* __restrict__ lc) {
  __shared__ int hcnt[NPAD];
  const int t = threadIdx.x, b = blockIdx.x;
  #pragma unroll
  for (int i = 0; i < 4; ++i) hcnt[t + 256 * i] = 0;
  __syncthreads();
  #pragma unroll
  for (int i = 0; i < 8; ++i) atomicAdd(&hcnt[idx[b * SEQ + i * 256 + t]], 1);
  __syncthreads();
  #pragma unroll
  for (int i = 0; i < 4; ++i) {
    int n = t + 256 * i;
    int c = hcnt[n];
    lc[b * NPAD + n] = (n < NMEM && c > 0) ? log2f((float)c) : -1e30f;
  }
}

// ---------------------------------------------------------------------------
// Attention over the 1000-entry table, exp2 static softmax, double-buffered
// K/V staging (verified round 7). 4 waves x 64 q-rows, grid (8,16,4).
// ---------------------------------------------------------------------------
__global__ __launch_bounds__(256) void attn_table(const __bf16* __restrict__ qph,
                                                  const __bf16* __restrict__ Ktab,
                                                  const __bf16* __restrict__ VtTp,
                                                  const float* __restrict__ lc2,
                                                  __bf16* __restrict__ attn_bf) {
  extern __shared__ char smem[];
  char* sK = smem;                 // [2][8192]: K tiles [64 key][64 d]
  char* sV = smem + 16384;         // [2][8192]: V^T tiles [64 d][64 key']
  char* sP = smem + 32768;         // [4 waves][64 rows][64 keys'], XOR-swizzled

  const int t = threadIdx.x;
  const int wq = t >> 6, lane = t & 63, l15 = lane & 15, g = lane >> 4;
  const int b = blockIdx.z, h = blockIdx.y;
  const int q0 = blockIdx.x * 256 + wq * 64;

  bf16x8 qa[4][2];
  #pragma unroll
  for (int mi = 0; mi < 4; ++mi)
    #pragma unroll
    for (int ks = 0; ks < 2; ++ks)
      qa[mi][ks] = *(const bf16x8*)&qph[(size_t)(b * SEQ + q0 + mi * 16 + l15) * DIM +
                                        h * DHEAD + ks * 32 + g * 8];

  f32x4 O[4][4];
  #pragma unroll
  for (int mi = 0; mi < 4; ++mi)
    #pragma unroll
    for (int fd = 0; fd < 4; ++fd) O[mi][fd] = (f32x4){0.f, 0.f, 0.f, 0.f};
  float lsum[4][4];
  #pragma unroll
  for (int mi = 0; mi < 4; ++mi)
    #pragma unroll
    for (int r = 0; r < 4; ++r) lsum[mi][r] = 0.f;

  const __bf16* Kb = Ktab + (size_t)b * NPAD * DHEAD;
  const __bf16* Vb = VtTp + (size_t)b * DHEAD * NPAD;
  const float* lcb = lc2 + b * NPAD;
  char* sPw = sP + wq * 8192;

  auto STAGE = [&](int buf, int tile) {
    const int n0 = tile * 64;
    #pragma unroll
    for (int i = 0; i < 2; ++i) {
      int c = i * 256 + t, row = c >> 3, s = c & 7, sl = s ^ (row & 7);
      GLOAD16(&Kb[(size_t)(n0 + row) * DHEAD + sl * 8], sK + buf * 8192 + i * 4096 + wq * 1024);
      GLOAD16(&Vb[(size_t)row * NPAD + n0 + sl * 8], sV + buf * 8192 + i * 4096 + wq * 1024);
    }
  };

  STAGE(0, 0);
  __syncthreads();
  int cur = 0;

  for (int tile = 0; tile < NPAD / 64; ++tile) {
    if (tile + 1 < NPAD / 64) STAGE(cur ^ 1, tile + 1);  // prefetch next

    const int n0 = tile * 64;
    float lcv[4];
    #pragma unroll
    for (int ni = 0; ni < 4; ++ni) lcv[ni] = lcb[n0 + ni * 16 + l15];

    bf16x8 kf[2][4];
    #pragma unroll
    for (int ks = 0; ks < 2; ++ks)
      #pragma unroll
      for (int ni = 0; ni < 4; ++ni)
        kf[ks][ni] = *(const bf16x8*)(sK + cur * 8192 + (ni * 16 + l15) * 128 +
                                      (((ks * 4 + g) ^ (l15 & 7)) * 16));

    #pragma unroll
    for (int mi = 0; mi < 4; ++mi) {
      f32x4 S[4];
      #pragma unroll
      for (int ni = 0; ni < 4; ++ni) S[ni] = (f32x4){0.f, 0.f, 0.f, 0.f};
      __builtin_amdgcn_s_setprio(1);
      #pragma unroll
      for (int ks = 0; ks < 2; ++ks)
        #pragma unroll
        for (int ni = 0; ni < 4; ++ni)
          S[ni] = mfma16(qa[mi][ks], kf[ks][ni], S[ni]);
      __builtin_amdgcn_s_setprio(0);
      #pragma unroll
      for (int r = 0; r < 4; ++r) {
        int row = mi * 16 + g * 4 + r;
        bf16x4 p4;
        float rs = 0.f;
        #pragma unroll
        for (int ni = 0; ni < 4; ++ni) {
          float p = __builtin_amdgcn_exp2f(S[ni][r] + lcv[ni]);
          rs += p;
          p4[ni] = (__bf16)p;
        }
        *(bf16x4*)(sPw + row * 128 + ((l15 * 8) ^ ((row & 7) << 4))) = p4;
        lsum[mi][r] += rs;
      }
    }

    #pragma unroll
    for (int ks = 0; ks < 2; ++ks) {
      bf16x8 vf[4];
      #pragma unroll
      for (int fd = 0; fd < 4; ++fd)
        vf[fd] = *(const bf16x8*)(sV + cur * 8192 + (fd * 16 + l15) * 128 +
                                  (((ks * 4 + g) ^ (l15 & 7)) * 16));
      __builtin_amdgcn_s_setprio(1);
      #pragma unroll
      for (int mi = 0; mi < 4; ++mi) {
        int row = mi * 16 + l15;
        bf16x8 pa = *(const bf16x8*)(sPw + row * 128 +
                                     ((ks * 64 + g * 16) ^ ((row & 7) << 4)));
        #pragma unroll
        for (int fd = 0; fd < 4; ++fd)
          O[mi][fd] = mfma16(pa, vf[fd], O[mi][fd]);
      }
      __builtin_amdgcn_s_setprio(0);
    }

    __syncthreads();
    cur ^= 1;
  }

  #pragma unroll
  for (int mi = 0; mi < 4; ++mi)
    #pragma unroll
    for (int r = 0; r < 4; ++r) {
      float rs = lsum[mi][r];
      #pragma unroll
      for (int off = 1; off < 16; off <<= 1) rs += __shfl_xor(rs, off);
      float inv = 1.f / rs;
      size_t row = (size_t)(b * SEQ + q0 + mi * 16 + g * 4 + r);
      #pragma unroll
      for (int fd = 0; fd < 4; ++fd)
        attn_bf[row * DIM + h * DHEAD + fd * 16 + l15] = (__bf16)(O[mi][fd][r] * inv);
    }
}

// ---------------------------------------------------------------------------
// Casts
// ---------------------------------------------------------------------------
__global__ __launch_bounds__(256) void cast_w_t(const float* __restrict__ in,
                                                __bf16* __restrict__ oh,
                                                __bf16* __restrict__ ol,
                                                int writeLo) {
  __shared__ float tile[64][65];
  const int t = threadIdx.x;
  const int k0 = blockIdx.x * 64, n0 = blockIdx.y * 64;
  #pragma unroll
  for (int i = 0; i < 16; ++i) {
    int e = t + i * 256, r = e >> 6, c = e & 63;
    tile[r][c] = in[(size_t)(k0 + r) * DIM + n0 + c];
  }
  __syncthreads();
  #pragma unroll
  for (int i = 0; i < 16; ++i) {
    int e = t + i * 256, r = e >> 6, c = e & 63;
    float v = tile[c][r];
    __bf16 h = (__bf16)v;
    oh[(size_t)(n0 + r) * DIM + k0 + c] = h;
    if (writeLo) ol[(size_t)(n0 + r) * DIM + k0 + c] = (__bf16)(v - (float)h);
  }
}

// w_kv [1024][128] f32 -> [128][1024] bf16 hi/lo
__global__ __launch_bounds__(256) void cast_wkv_t(const float* __restrict__ in,
                                                  __bf16* __restrict__ oh,
                                                  __bf16* __restrict__ ol) {
  __shared__ float tile[64][65];
  const int t = threadIdx.x;
  const int k0 = blockIdx.x * 64, n0 = blockIdx.y * 64;
  #pragma unroll
  for (int i = 0; i < 16; ++i) {
    int e = t + i * 256, r = e >> 6, c = e & 63;
    tile[r][c] = in[(size_t)(k0 + r) * 128 + n0 + c];
  }
  __syncthreads();
  #pragma unroll
  for (int i = 0; i < 16; ++i) {
    int e = t + i * 256, r = e >> 6, c = e & 63;
    float v = tile[c][r];
    __bf16 h = (__bf16)v;
    oh[(size_t)(n0 + r) * DIM + k0 + c] = h;
    ol[(size_t)(n0 + r) * DIM + k0 + c] = (__bf16)(v - (float)h);
  }
}

__global__ __launch_bounds__(256) void cast_mem(const float* __restrict__ mem,
                                                __bf16* __restrict__ mh,
                                                __bf16* __restrict__ ml) {
  size_t e = ((size_t)blockIdx.x * 256 + threadIdx.x) * 8;
  int d = (int)(e & 1023);
  size_t rn = e >> 10;
  int n = (int)(rn & 1023), b = (int)(rn >> 10);
  bf16x8 h8, l8;
  if (n < NMEM) {
    const float* p = mem + ((size_t)b * NMEM + n) * DIM + d;
    #pragma unroll
    for (int j = 0; j < 8; ++j) {
      float v = p[j];
      __bf16 h = (__bf16)v;
      h8[j] = h; l8[j] = (__bf16)(v - (float)h);
    }
  } else {
    #pragma unroll
    for (int j = 0; j < 8; ++j) { h8[j] = (__bf16)0.f; l8[j] = (__bf16)0.f; }
  }
  *(bf16x8*)(mh + e) = h8;
  *(bf16x8*)(ml + e) = l8;
}

// ---------------------------------------------------------------------------
extern "C" void kernel_launch(void* const* d_in, const int* in_sizes, int n_in,
                              void* d_out, int out_size, void* d_ws, size_t ws_size,
                              hipStream_t stream) {
  const float* q        = (const float*)d_in[0];
  const float* mem      = (const float*)d_in[2];
  const float* w_q      = (const float*)d_in[3];
  const float* w_kv     = (const float*)d_in[4];
  const float* w_concat = (const float*)d_in[5];
  float* out = (float*)d_out;

  char* wsb = (char*)d_ws;
  __bf16* memh   = (__bf16*)(wsb + 0);                  //  8 MiB
  __bf16* meml   = (__bf16*)(wsb + 8388608);            //  8 MiB
  __bf16* wqt_h  = (__bf16*)(wsb + 16777216);           //  2 MiB
  __bf16* wqt_l  = (__bf16*)(wsb + 18874368);           //  2 MiB
  __bf16* wct    = (__bf16*)(wsb + 20971520);           //  2 MiB
  __bf16* Ktab   = (__bf16*)(wsb + 23068672);           //  512 KiB
  __bf16* VtT    = (__bf16*)(wsb + 23592960);           //  512 KiB
  float*  lc     = (float*) (wsb + 24117248);           //  16 KiB
  float*  pv     = (float*) (wsb + 24133632);           //  256 KiB
  int*    pi     = (int*)   (wsb + 24395776);           //  256 KiB
  int*    idx    = (int*)   (wsb + 24657920);           //  32 KiB
  __bf16* wkvT_h = (__bf16*)(wsb + 24690688);           //  256 KiB
  __bf16* wkvT_l = (__bf16*)(wsb + 24952832);           //  256 KiB
  __bf16* qph    = (__bf16*)(wsb + 25214976);           // 16 MiB
  __bf16* qpl    = (__bf16*)(wsb + 41992192);           // 16 MiB (reused as attn_bf)
  __bf16* attn_bf = qpl;

  cast_w_t<<<dim3(16, 16), 256, 0, stream>>>(w_q, wqt_h, wqt_l, 1);
  cast_w_t<<<dim3(16, 16), 256, 0, stream>>>(w_concat, wct, (__bf16*)0, 0);
  cast_wkv_t<<<dim3(16, 2), 256, 0, stream>>>(w_kv, wkvT_h, wkvT_l);
  cast_mem<<<dim3(2048), 256, 0, stream>>>(mem, memh, meml);

  // qp = q @ w_q, pre-scaled by QSCALE -> qph/qpl  (dbuf: 64 KiB LDS)
  gemm3<1, 3, MODE_HILO><<<dim3(64, 8, 1), 256, 65536, stream>>>(
      (const void*)q, (const __bf16*)0, wqt_h, wqt_l, 0, 0,
      (float*)0, qph, qpl, (float*)0, (int*)0);

  // K/V tables over all memories: (memh/meml) @ w_kv^T -> Ktab, VtT (permuted)
  gemm3<0, 3, MODE_KV><<<dim3(BATCH * NPAD / 128, 1, 1), 256, 65536, stream>>>(
      (const void*)memh, meml, wkvT_h, wkvT_l, 0, 0,
      (float*)0, Ktab, VtT, (float*)0, (int*)0);

  // kNN scores + argmax partials (scores scaled by QSCALE: argmax-invariant)
  gemm3<0, 3, MODE_ARGMAX><<<dim3(16, 8, 4), 256, 65536, stream>>>(
      (const void*)qph, qpl, memh, meml, 2048, (long)NPAD * DIM,
      (float*)0, (__bf16*)0, (__bf16*)0, pv, pi);
  knn_reduce<<<dim3(32), 256, 0, stream>>>(pv, pi, idx);

  // counts -> log2 bias
  hist_lc<<<dim3(BATCH), 256, 0, stream>>>(idx, lc);

  // attention over the table (double-buffered staging, 64 KiB LDS)
  attn_table<<<dim3(SEQ / 256, NHEAD, BATCH), 256, 65536, stream>>>(
      qph, Ktab, VtT, lc, attn_bf);

  // out = attn @ w_concat (dbuf: 32 KiB LDS)
  gemm3<0, 1, MODE_C><<<dim3(64, 8, 1), 256, 32768, stream>>>(
      (const void*)attn_bf, (const __bf16*)0, wct, (const __bf16*)0, 0, 0,
      out, (__bf16*)0, (__bf16*)0, (float*)0, (int*)0);
}